// Round 19
// baseline (340.693 us; speedup 1.0000x reference)
//
#include <hip/hip_runtime.h>
#include <hip/hip_bf16.h>
#include <math.h>

#define DIMN   1024
#define HEADS  16
#define DHEAD  64
#define CTXD   768
#define FFH    4096
#define NTOK   4096
#define SEQ    2048
#define NCTX   77
#define CTOK   154

typedef unsigned short u16;
typedef __bf16 bf16x8 __attribute__((ext_vector_type(8)));
typedef float  f32x4  __attribute__((ext_vector_type(4)));

__device__ __forceinline__ u16 f2bf(float f) {
  union { float f; unsigned u; } c; c.f = f;
  unsigned r = c.u + 0x7FFFu + ((c.u >> 16) & 1u);
  return (u16)(r >> 16);
}
__device__ __forceinline__ float bf2f(u16 h) {
  union { unsigned u; float f; } c; c.u = ((unsigned)h) << 16; return c.f;
}

__device__ __forceinline__ void gload16(const void* g, void* l) {
  __builtin_amdgcn_global_load_lds(
      (__attribute__((address_space(1))) void*)(void*)(g),
      (__attribute__((address_space(3))) void*)(l), 16, 0, 0);
}

__device__ __forceinline__ f32x4 mfma16(bf16x8 a, bf16x8 b, f32x4 c) {
  return __builtin_amdgcn_mfma_f32_16x16x32_bf16(a, b, c, 0, 0, 0);
}

// ---------------- prologue work-list: 10 weight transposes + LN1 + ctx conversion
struct WAll {
  int nw;
  int start[10];
  const float* s[10];
  u16* d[10];
  int K[10];
  int N[10];
  int lnStart, ccStart;
  const float* x; const float* g1; const float* be1; u16* hb;
  const float* ctx; u16* ctxb;
};

__global__ __launch_bounds__(256)
void wconvA_k(WAll wa)
{
  __shared__ u16 t[64][65];
  __shared__ float ss[4], qq[4];
  const int bid = blockIdx.x;
  const int tid = threadIdx.x;

  if (bid >= wa.ccStart) {
    const int i = (bid - wa.ccStart) * 256 + tid;
    if (i < CTOK * CTXD) wa.ctxb[i] = f2bf(wa.ctx[i]);
    return;
  }
  if (bid >= wa.lnStart) {
    const int row = bid - wa.lnStart;
    const float4 v = *(const float4*)&wa.x[(size_t)row * DIMN + tid * 4];
    float s = v.x + v.y + v.z + v.w;
    float q = v.x*v.x + v.y*v.y + v.z*v.z + v.w*v.w;
#pragma unroll
    for (int off = 32; off; off >>= 1) { s += __shfl_xor(s, off); q += __shfl_xor(q, off); }
    const int wave = tid >> 6;
    if ((tid & 63) == 0) { ss[wave] = s; qq[wave] = q; }
    __syncthreads();
    s = ss[0] + ss[1] + ss[2] + ss[3];
    q = qq[0] + qq[1] + qq[2] + qq[3];
    const float mu = s * (1.0f / DIMN);
    const float var = q * (1.0f / DIMN) - mu * mu;
    const float rs = rsqrtf(var + 1e-5f);
    const float4 gv = *(const float4*)&wa.g1[tid * 4];
    const float4 bv = *(const float4*)&wa.be1[tid * 4];
    ushort4 r;
    r.x = f2bf((v.x - mu) * rs * gv.x + bv.x);
    r.y = f2bf((v.y - mu) * rs * gv.y + bv.y);
    r.z = f2bf((v.z - mu) * rs * gv.z + bv.z);
    r.w = f2bf((v.w - mu) * rs * gv.w + bv.w);
    *(ushort4*)&wa.hb[(size_t)row * DIMN + tid * 4] = r;
    return;
  }

  int w = 0;
  while (w + 1 < wa.nw && bid >= wa.start[w + 1]) ++w;
  const int local = bid - wa.start[w];
  const float* __restrict__ W  = wa.s[w];
  u16* __restrict__       WT   = wa.d[w];
  const int K = wa.K[w], N = wa.N[w];
  const int tilesX = N >> 6;
  const int n0 = (local % tilesX) * 64;
  const int k0 = (local / tilesX) * 64;
  const int rr = tid >> 4, cc = tid & 15;
#pragma unroll
  for (int i = 0; i < 4; ++i) {
    int kr = rr + i * 16;
    const float4 v = *(const float4*)&W[(size_t)(k0 + kr) * N + n0 + cc * 4];
    t[kr][cc*4+0] = f2bf(v.x); t[kr][cc*4+1] = f2bf(v.y);
    t[kr][cc*4+2] = f2bf(v.z); t[kr][cc*4+3] = f2bf(v.w);
  }
  __syncthreads();
#pragma unroll
  for (int i = 0; i < 4; ++i) {
    int nr = rr + i * 16;
    int r0 = cc * 4;
    ushort4 o;
    o.x = t[r0+0][nr]; o.y = t[r0+1][nr]; o.z = t[r0+2][nr]; o.w = t[r0+3][nr];
    *(ushort4*)&WT[(size_t)(n0 + nr) * K + k0 + r0] = o;
  }
}

// ---------------- LayerNorm: bf16 row[1024] -> bf16
__global__ __launch_bounds__(256)
void ln_b_k(const u16* __restrict__ x, const float* __restrict__ gm,
            const float* __restrict__ bt, u16* __restrict__ o)
{
  int row = blockIdx.x;
  int tid = threadIdx.x;
  const ushort4 u = *(const ushort4*)&x[(size_t)row * DIMN + tid * 4];
  float4 v;
  v.x = bf2f(u.x); v.y = bf2f(u.y); v.z = bf2f(u.z); v.w = bf2f(u.w);
  float s = v.x + v.y + v.z + v.w;
  float q = v.x*v.x + v.y*v.y + v.z*v.z + v.w*v.w;
#pragma unroll
  for (int off = 32; off; off >>= 1) { s += __shfl_xor(s, off); q += __shfl_xor(q, off); }
  __shared__ float ss[4], qq[4];
  int wave = tid >> 6;
  if ((tid & 63) == 0) { ss[wave] = s; qq[wave] = q; }
  __syncthreads();
  s = ss[0] + ss[1] + ss[2] + ss[3];
  q = qq[0] + qq[1] + qq[2] + qq[3];
  float mu = s * (1.0f / DIMN);
  float var = q * (1.0f / DIMN) - mu * mu;
  float rs = rsqrtf(var + 1e-5f);
  const float4 gv = *(const float4*)&gm[tid * 4];
  const float4 bv = *(const float4*)&bt[tid * 4];
  ushort4 r;
  r.x = f2bf((v.x - mu) * rs * gv.x + bv.x);
  r.y = f2bf((v.y - mu) * rs * gv.y + bv.y);
  r.z = f2bf((v.z - mu) * rs * gv.z + bv.z);
  r.w = f2bf((v.w - mu) * rs * gv.w + bv.w);
  *(ushort4*)&o[(size_t)row * DIMN + tid * 4] = r;
}

// ---------------- QKV GEMM, BK=64: M=4096 N=3072 K=1024, routed epilogue
__global__ __launch_bounds__(512, 2)
void qkv64_k(const u16* __restrict__ A, const u16* __restrict__ Bt,
             u16* __restrict__ qb, u16* __restrict__ kb, u16* __restrict__ vtb)
{
  __shared__ __align__(16) u16 As[2][128 * 64];
  __shared__ __align__(16) u16 Bs[2][128 * 64];
  const int tid = threadIdx.x;
  const int lane = tid & 63, wave = tid >> 6;
  const int wr = wave >> 1, wc = wave & 1;
  const int g = lane >> 4, r16 = lane & 15;
  const int m0 = blockIdx.x * 128, n0 = blockIdx.y * 128;
  const int K = 1024;

  f32x4 acc[2][4] = {};

  int aro[2], bro[2], scs[2];
#pragma unroll
  for (int i = 0; i < 2; ++i) {
    const int c = tid + i * 512;
    const int r = c >> 3, ch = c & 7;
    scs[i] = ch ^ (r & 7);
    aro[i] = m0 + r;
    bro[i] = n0 + r;
  }

  auto stage = [&](int buf, int kt) {
#pragma unroll
    for (int i = 0; i < 2; ++i) {
      const int c = tid + i * 512;
      gload16(A  + (size_t)aro[i] * K + kt + scs[i] * 8, &As[buf][c * 8]);
      gload16(Bt + (size_t)bro[i] * K + kt + scs[i] * 8, &Bs[buf][c * 8]);
    }
  };

  stage(0, 0);

  const int nkt = K >> 6;
  for (int t = 0; t < nkt; ++t) {
    const int cur = t & 1;
    if (t + 1 < nkt) {
      stage(cur ^ 1, (t + 1) << 6);
      asm volatile("s_waitcnt vmcnt(4)" ::: "memory");
    } else {
      asm volatile("s_waitcnt vmcnt(0)" ::: "memory");
    }
    __builtin_amdgcn_s_barrier();

#pragma unroll
    for (int ks = 0; ks < 2; ++ks) {
      bf16x8 af[2], bfr[4];
#pragma unroll
      for (int mi = 0; mi < 2; ++mi) {
        int r = wr * 32 + mi * 16 + r16;
        int cph = (ks * 4 + g) ^ (r & 7);
        af[mi] = *(const bf16x8*)&As[cur][(r * 8 + cph) * 8];
      }
#pragma unroll
      for (int ni = 0; ni < 4; ++ni) {
        int r = wc * 64 + ni * 16 + r16;
        int cph = (ks * 4 + g) ^ (r & 7);
        bfr[ni] = *(const bf16x8*)&Bs[cur][(r * 8 + cph) * 8];
      }
      __builtin_amdgcn_s_setprio(1);
#pragma unroll
      for (int mi = 0; mi < 2; ++mi)
#pragma unroll
        for (int ni = 0; ni < 4; ++ni)
          acc[mi][ni] = mfma16(af[mi], bfr[ni], acc[mi][ni]);
      __builtin_amdgcn_s_setprio(0);
    }

    __builtin_amdgcn_s_barrier();
  }

  const int grp = n0 >> 10;
#pragma unroll
  for (int ni = 0; ni < 4; ++ni) {
    int col = n0 + wc * 64 + ni * 16 + r16;
    const int c1 = col & 1023;
#pragma unroll
    for (int mi = 0; mi < 2; ++mi) {
#pragma unroll
      for (int rg = 0; rg < 4; ++rg) {
        int row = m0 + wr * 32 + mi * 16 + g * 4 + rg;
        float v = acc[mi][ni][rg];
        if (grp == 0) {
          qb[(size_t)row * 1024 + c1] = f2bf(v);
        } else if (grp == 1) {
          kb[(size_t)row * 1024 + c1] = f2bf(v);
        } else {
          int b = row >> 11, srow_ = row & 2047;
          int jg = srow_ >> 6, j = srow_ & 63;
          int pos = jg * 64 + ((j & 15) << 2) + (j >> 4);
          vtb[((size_t)b * HEADS * DHEAD + c1) * SEQ + pos] = f2bf(v);
        }
      }
    }
  }
}

// ---------------- GEMM BK=128 for grid=256 (1 block/CU) epilogue GEMMs.
// MODE 6: out bf16 = acc + bias + residf (f32 resid)
// MODE 7: out bf16 = acc + bias + residb (bf16 resid)
// MODE 8: out f32  = acc + bias + residb (bf16 resid)
template<int MODE>
__global__ __launch_bounds__(512, 1)
void gemm128_k(const u16* __restrict__ A, const u16* __restrict__ Bt,
               int M, int N, int K,
               const float* __restrict__ bias, const float* __restrict__ residf,
               const u16* __restrict__ residb,
               u16* __restrict__ obf, float* __restrict__ of32)
{
  __shared__ __align__(16) u16 As[2][128 * 128];   // 64 KB
  __shared__ __align__(16) u16 Bs[2][128 * 128];   // 64 KB
  const int tid = threadIdx.x;
  const int lane = tid & 63, wave = tid >> 6;
  const int wr = wave >> 1, wc = wave & 1;
  const int g = lane >> 4, r16 = lane & 15;
  const int m0 = blockIdx.x * 128, n0 = blockIdx.y * 128;

  f32x4 acc[2][4] = {};

  int aro[4], bro[4], scs[4];
#pragma unroll
  for (int i = 0; i < 4; ++i) {
    const int c = tid + i * 512;
    const int r = c >> 4, ch = c & 15;
    scs[i] = ch ^ (r & 15);
    aro[i] = m0 + r;
    bro[i] = n0 + r;
  }

  auto stage = [&](int buf, int kt) {
#pragma unroll
    for (int i = 0; i < 4; ++i) {
      const int c = tid + i * 512;
      gload16(A  + (size_t)aro[i] * K + kt + scs[i] * 8, &As[buf][c * 8]);
      gload16(Bt + (size_t)bro[i] * K + kt + scs[i] * 8, &Bs[buf][c * 8]);
    }
  };

  stage(0, 0);

  const int nkt = K >> 7;
  for (int t = 0; t < nkt; ++t) {
    const int cur = t & 1;
    if (t + 1 < nkt) {
      stage(cur ^ 1, (t + 1) << 7);
      asm volatile("s_waitcnt vmcnt(8)" ::: "memory");
    } else {
      asm volatile("s_waitcnt vmcnt(0)" ::: "memory");
    }
    __builtin_amdgcn_s_barrier();

#pragma unroll
    for (int ks = 0; ks < 4; ++ks) {
      bf16x8 af[2], bfr[4];
#pragma unroll
      for (int mi = 0; mi < 2; ++mi) {
        int r = wr * 32 + mi * 16 + r16;
        int cph = (ks * 4 + g) ^ (r & 15);
        af[mi] = *(const bf16x8*)&As[cur][(r * 16 + cph) * 8];
      }
#pragma unroll
      for (int ni = 0; ni < 4; ++ni) {
        int r = wc * 64 + ni * 16 + r16;
        int cph = (ks * 4 + g) ^ (r & 15);
        bfr[ni] = *(const bf16x8*)&Bs[cur][(r * 16 + cph) * 8];
      }
      __builtin_amdgcn_s_setprio(1);
#pragma unroll
      for (int mi = 0; mi < 2; ++mi)
#pragma unroll
        for (int ni = 0; ni < 4; ++ni)
          acc[mi][ni] = mfma16(af[mi], bfr[ni], acc[mi][ni]);
      __builtin_amdgcn_s_setprio(0);
    }

    __builtin_amdgcn_s_barrier();
  }

#pragma unroll
  for (int ni = 0; ni < 4; ++ni) {
    int col = n0 + wc * 64 + ni * 16 + r16;
    float bv = bias[col];
#pragma unroll
    for (int mi = 0; mi < 2; ++mi) {
      f32x4 c = acc[mi][ni];
#pragma unroll
      for (int rg = 0; rg < 4; ++rg) {
        int row = m0 + wr * 32 + mi * 16 + g * 4 + rg;
        size_t o = (size_t)row * N + col;
        float v = c[rg] + bv;
        if constexpr (MODE == 6) {
          obf[o] = f2bf(v + residf[o]);
        } else if constexpr (MODE == 7) {
          obf[o] = f2bf(v + bf2f(residb[o]));
        } else {  // MODE 8
          of32[o] = v + bf2f(residb[o]);
        }
      }
    }
  }
}

// ---------------- merged Q2 (BK=128, 256 blocks) + KV2 (BK=32, 32 blocks)
// grid = 288 x 512 threads; 128 KB LDS (1 block/CU); KV2 aliases into AsB[0]/BsB[0].
__global__ __launch_bounds__(512, 1)
void q2kv2_k(const u16* __restrict__ hb, const u16* __restrict__ WqT2,
             u16* __restrict__ qb,
             const u16* __restrict__ ctxb, const u16* __restrict__ WkT2,
             u16* __restrict__ k2b, u16* __restrict__ vt2b)
{
  __shared__ __align__(16) u16 AsB[2][128 * 128];   // 64 KB
  __shared__ __align__(16) u16 BsB[2][128 * 128];   // 64 KB
  const int tid = threadIdx.x;
  const int lane = tid & 63, wave = tid >> 6;
  const int wr = wave >> 1, wc = wave & 1;
  const int g = lane >> 4, r16 = lane & 15;
  const int bid = blockIdx.x;

  if (bid < 256) {
    // ======== Q2: M=4096 N=1024 K=1024, BK=128 (gemm128 body), out bf16 no bias ========
    const int K = 1024;
    const int m0 = (bid & 31) * 128, n0 = (bid >> 5) * 128;
    f32x4 acc[2][4] = {};

    int aro[4], bro[4], scs[4];
#pragma unroll
    for (int i = 0; i < 4; ++i) {
      const int c = tid + i * 512;
      const int r = c >> 4, ch = c & 15;
      scs[i] = ch ^ (r & 15);
      aro[i] = m0 + r;
      bro[i] = n0 + r;
    }
    auto stage = [&](int buf, int kt) {
#pragma unroll
      for (int i = 0; i < 4; ++i) {
        const int c = tid + i * 512;
        gload16(hb   + (size_t)aro[i] * K + kt + scs[i] * 8, &AsB[buf][c * 8]);
        gload16(WqT2 + (size_t)bro[i] * K + kt + scs[i] * 8, &BsB[buf][c * 8]);
      }
    };
    stage(0, 0);
    const int nkt = K >> 7;                           // 8
    for (int t = 0; t < nkt; ++t) {
      const int cur = t & 1;
      if (t + 1 < nkt) {
        stage(cur ^ 1, (t + 1) << 7);
        asm volatile("s_waitcnt vmcnt(8)" ::: "memory");
      } else {
        asm volatile("s_waitcnt vmcnt(0)" ::: "memory");
      }
      __builtin_amdgcn_s_barrier();
#pragma unroll
      for (int ks = 0; ks < 4; ++ks) {
        bf16x8 af[2], bfr[4];
#pragma unroll
        for (int mi = 0; mi < 2; ++mi) {
          int r = wr * 32 + mi * 16 + r16;
          int cph = (ks * 4 + g) ^ (r & 15);
          af[mi] = *(const bf16x8*)&AsB[cur][(r * 16 + cph) * 8];
        }
#pragma unroll
        for (int ni = 0; ni < 4; ++ni) {
          int r = wc * 64 + ni * 16 + r16;
          int cph = (ks * 4 + g) ^ (r & 15);
          bfr[ni] = *(const bf16x8*)&BsB[cur][(r * 16 + cph) * 8];
        }
        __builtin_amdgcn_s_setprio(1);
#pragma unroll
        for (int mi = 0; mi < 2; ++mi)
#pragma unroll
          for (int ni = 0; ni < 4; ++ni)
            acc[mi][ni] = mfma16(af[mi], bfr[ni], acc[mi][ni]);
        __builtin_amdgcn_s_setprio(0);
      }
      __builtin_amdgcn_s_barrier();
    }
#pragma unroll
    for (int ni = 0; ni < 4; ++ni) {
      int col = n0 + wc * 64 + ni * 16 + r16;
#pragma unroll
      for (int mi = 0; mi < 2; ++mi) {
#pragma unroll
        for (int rg = 0; rg < 4; ++rg) {
          int row = m0 + wr * 32 + mi * 16 + g * 4 + rg;
          qb[(size_t)row * 1024 + col] = f2bf(acc[mi][ni][rg]);
        }
      }
    }
  } else {
    // ======== KV2: M=CTOK N=2048 K=768, BK=32, mode-5 epilogue (unchanged) ========
    const int K = 768, M = CTOK;
    const int local = bid - 256;
    const int m0 = (local & 1) * 128, n0 = (local >> 1) * 128;
    u16* As = &AsB[0][0];
    u16* Bs = &BsB[0][0];
    const int BUFS = 128 * 32;
    f32x4 acc[2][4] = {};

    const int srow = tid >> 2;
    const int sch  = tid & 3;
    const int schs = sch ^ ((srow >> 1) & 3);
    const int arow = (m0 + srow > M - 1) ? (M - 1) : (m0 + srow);
    const size_t abase = (size_t)arow * K + schs * 8;
    const size_t bbase = (size_t)(n0 + srow) * K + schs * 8;

    auto stage = [&](int buf, int kt) {
      gload16(ctxb + abase + kt, &As[buf * BUFS + tid * 8]);
      gload16(WkT2 + bbase + kt, &Bs[buf * BUFS + tid * 8]);
    };
    stage(0, 0);
    const int nkt = K >> 5;
    for (int t = 0; t < nkt; ++t) {
      const int cur = t & 1;
      if (t + 1 < nkt) {
        stage(cur ^ 1, (t + 1) << 5);
        asm volatile("s_waitcnt vmcnt(2)" ::: "memory");
      } else {
        asm volatile("s_waitcnt vmcnt(0)" ::: "memory");
      }
      __builtin_amdgcn_s_barrier();

      bf16x8 af[2], bfr[4];
#pragma unroll
      for (int mi = 0; mi < 2; ++mi) {
        int r = wr * 32 + mi * 16 + r16;
        int cph = g ^ ((r >> 1) & 3);
        af[mi] = *(const bf16x8*)&As[cur * BUFS + (r * 4 + cph) * 8];
      }
#pragma unroll
      for (int ni = 0; ni < 4; ++ni) {
        int r = wc * 64 + ni * 16 + r16;
        int cph = g ^ ((r >> 1) & 3);
        bfr[ni] = *(const bf16x8*)&Bs[cur * BUFS + (r * 4 + cph) * 8];
      }
      __builtin_amdgcn_s_setprio(1);
#pragma unroll
      for (int mi = 0; mi < 2; ++mi)
#pragma unroll
        for (int ni = 0; ni < 4; ++ni)
          acc[mi][ni] = mfma16(af[mi], bfr[ni], acc[mi][ni]);
      __builtin_amdgcn_s_setprio(0);

      __builtin_amdgcn_s_barrier();
    }

    const int grp = n0 >> 10;
#pragma unroll
    for (int ni = 0; ni < 4; ++ni) {
      int col = n0 + wc * 64 + ni * 16 + r16;
      const int c1 = col & 1023;
#pragma unroll
      for (int mi = 0; mi < 2; ++mi) {
#pragma unroll
        for (int rg = 0; rg < 4; ++rg) {
          int row = m0 + wr * 32 + mi * 16 + g * 4 + rg;
          if (row < M) {
            float v = acc[mi][ni][rg];
            if (grp == 0) {
              k2b[(size_t)row * 1024 + c1] = f2bf(v);
            } else {
              int b = row / NCTX, srow_ = row - b * NCTX;
              int jg = srow_ >> 6, j = srow_ & 63;
              int pos = jg * 64 + ((j & 15) << 2) + (j >> 4);
              vt2b[((size_t)b * HEADS * DHEAD + c1) * 128 + pos] = f2bf(v);
            }
          }
        }
      }
    }
  }
}

// ---------------- fused GEGLU GEMM: 512 thr, 128x128, 2-buf counted vmcnt, XCD swizzle
__global__ __launch_bounds__(512, 2)
void geglu_k(const u16* __restrict__ A, const u16* __restrict__ B1t,
             const u16* __restrict__ B2t,
             const float* __restrict__ ba, const float* __restrict__ bg,
             u16* __restrict__ out, int M, int N)
{
  __shared__ __align__(16) u16 As[2][128 * 32];
  __shared__ __align__(16) u16 B1s[2][128 * 32];
  __shared__ __align__(16) u16 B2s[2][128 * 32];
  const int tid = threadIdx.x;
  const int lane = tid & 63, wave = tid >> 6;
  const int wr = wave >> 1, wc = wave & 1;
  const int g = lane >> 4, r16 = lane & 15;
  {
    const int gx = gridDim.x;
    const int nwg = gx * gridDim.y;
    const int L = blockIdx.y * gx + blockIdx.x;
    const int nl = (L & 7) * (nwg >> 3) + (L >> 3);
    const int bx = nl % gx, by = nl / gx;
    const int m0 = bx * 128, n0 = by * 128;
    const int K = 1024;

    f32x4 acca[2][4] = {}, accg[2][4] = {};

    const int srow = tid >> 2;
    const int sch  = tid & 3;
    const int schs = sch ^ ((srow >> 1) & 3);
    const size_t abase = (size_t)(m0 + srow) * K + schs * 8;
    const size_t bbase = (size_t)(n0 + srow) * K + schs * 8;

    auto stage = [&](int buf, int kt) {
      gload16(A   + abase + kt, &As[buf][tid * 8]);
      gload16(B1t + bbase + kt, &B1s[buf][tid * 8]);
      gload16(B2t + bbase + kt, &B2s[buf][tid * 8]);
    };

    stage(0, 0);

    const int nkt = K >> 5;
    for (int t = 0; t < nkt; ++t) {
      const int cur = t & 1;
      if (t + 1 < nkt) {
        stage(cur ^ 1, (t + 1) << 5);
        asm volatile("s_waitcnt vmcnt(3)" ::: "memory");
      } else {
        asm volatile("s_waitcnt vmcnt(0)" ::: "memory");
      }
      __builtin_amdgcn_s_barrier();

      bf16x8 af[2], b1f[4], b2f[4];
#pragma unroll
      for (int mi = 0; mi < 2; ++mi) {
        int r = wr * 32 + mi * 16 + r16;
        int cph = g ^ ((r >> 1) & 3);
        af[mi] = *(const bf16x8*)&As[cur][(r * 4 + cph) * 8];
      }
#pragma unroll
      for (int ni = 0; ni < 4; ++ni) {
        int r = wc * 64 + ni * 16 + r16;
        int cph = g ^ ((r >> 1) & 3);
        b1f[ni] = *(const bf16x8*)&B1s[cur][(r * 4 + cph) * 8];
        b2f[ni] = *(const bf16x8*)&B2s[cur][(r * 4 + cph) * 8];
      }
      __builtin_amdgcn_s_setprio(1);
#pragma unroll
      for (int mi = 0; mi < 2; ++mi)
#pragma unroll
        for (int ni = 0; ni < 4; ++ni) {
          acca[mi][ni] = mfma16(af[mi], b1f[ni], acca[mi][ni]);
          accg[mi][ni] = mfma16(af[mi], b2f[ni], accg[mi][ni]);
        }
      __builtin_amdgcn_s_setprio(0);

      __builtin_amdgcn_s_barrier();
    }

#pragma unroll
    for (int ni = 0; ni < 4; ++ni) {
      int col = n0 + wc * 64 + ni * 16 + r16;
      float bva = ba[col], bvg = bg[col];
#pragma unroll
      for (int mi = 0; mi < 2; ++mi) {
#pragma unroll
        for (int rg = 0; rg < 4; ++rg) {
          int row = m0 + wr * 32 + mi * 16 + g * 4 + rg;
          float a  = acca[mi][ni][rg] + bva;
          float gt = accg[mi][ni][rg] + bvg;
          float gl = 0.5f * gt * (1.0f + erff(gt * 0.70710678f));
          out[(size_t)row * N + col] = f2bf(a * gl);
        }
      }
    }
  }
}

// ---------------- flash attention v6: 8 waves (256 q/block), KVBLK=128, XCD-affine
// grid MUST be (8, 32)
__global__ __launch_bounds__(512, 1)
void attn_k(const u16* __restrict__ q, const u16* __restrict__ k,
            const u16* __restrict__ vt, u16* __restrict__ o,
            int kvlen, int seqk, int vstride)
{
  __shared__ __align__(16) u16 Ks[2][128 * 64];
  __shared__ __align__(16) u16 Vs[2][64 * 128];
  __shared__ __align__(16) u16 Ps[8][32 * 136];
  const int tid = threadIdx.x, lane = tid & 63, wave = tid >> 6;
  const int g = lane >> 4, r16 = lane & 15;

  const int L  = blockIdx.y * 8 + blockIdx.x;
  const int c8 = L & 7, tt = L >> 3;
  const int bx = tt & 7;
  const int bh = c8 * 4 + (tt >> 3);

  const int b = bh >> 4, h = bh & 15;
  const int q0 = bx * 256 + wave * 32;
  const float C = 0.18033688f;

  bf16x8 aq[2][2];
#pragma unroll
  for (int qs = 0; qs < 2; ++qs) {
    const size_t qoff = (size_t)(b * SEQ + q0 + qs * 16 + r16) * DIMN + h * DHEAD;
#pragma unroll
    for (int kc = 0; kc < 2; ++kc)
      aq[qs][kc] = *(const bf16x8*)&q[qoff + kc * 32 + g * 8];
  }
  asm volatile("" :: "v"(aq[0][0]), "v"(aq[0][1]), "v"(aq[1][0]), "v"(aq[1][1]));

  f32x4 oacc[2][4] = {};
  float mi[2][4], li[2][4];
#pragma unroll
  for (int qs = 0; qs < 2; ++qs)
#pragma unroll
    for (int rg = 0; rg < 4; ++rg) { mi[qs][rg] = -3e38f; li[qs][rg] = 0.f; }

  const size_t vtbase = (size_t)(b * HEADS + h) * DHEAD * vstride;
  const size_t kbase  = (size_t)b * seqk * DIMN + h * DHEAD;
  const int nkv = (kvlen + 127) >> 7;

  auto stage = [&](int buf, int kv0) {
#pragma unroll
    for (int i = 0; i < 2; ++i) {
      const int c = tid + i * 512;
      const int row = c >> 3, ch = c & 7;
      const int chs = ch ^ (row & 7);
      int kr = kv0 + row; if (kr > kvlen - 1) kr = kvlen - 1;
      gload16(k + kbase + (size_t)kr * DIMN + chs * 8, &Ks[buf][c * 8]);
    }
#pragma unroll
    for (int i = 0; i < 2; ++i) {
      const int c = tid + i * 512;
      const int row = c >> 4, ch = c & 15;
      const int chs = ch ^ (row & 15);
      gload16(vt + vtbase + (size_t)row * vstride + kv0 + chs * 8, &Vs[buf][c * 8]);
    }
  };

  stage(0, 0);

  for (int kvb = 0; kvb < nkv; ++kvb) {
    const int kv0 = kvb * 128;
    const int cur = kvb & 1;
    if (kvb + 1 < nkv) {
      stage(cur ^ 1, kv0 + 128);
      asm volatile("s_waitcnt vmcnt(4)" ::: "memory");
    } else {
      asm volatile("s_waitcnt vmcnt(0)" ::: "memory");
    }
    __builtin_amdgcn_s_barrier();

    f32x4 sa[2][8];
#pragma unroll
    for (int qs = 0; qs < 2; ++qs)
#pragma unroll
      for (int st = 0; st < 8; ++st) sa[qs][st] = (f32x4){0.f, 0.f, 0.f, 0.f};
    __builtin_amdgcn_s_setprio(1);
#pragma unroll
    for (int st = 0; st < 8; ++st) {
      const int kvr = st * 16 + r16;
#pragma unroll
      for (int kc = 0; kc < 2; ++kc) {
        const int chs = (kc * 4 + g) ^ (kvr & 7);
        const bf16x8 kf = *(const bf16x8*)&Ks[cur][kvr * 64 + chs * 8];
        sa[0][st] = mfma16(aq[0][kc], kf, sa[0][st]);
        sa[1][st] = mfma16(aq[1][kc], kf, sa[1][st]);
      }
    }
    __builtin_amdgcn_s_setprio(0);

    if (kv0 + 128 > kvlen) {
#pragma unroll
      for (int st = 0; st < 8; ++st)
        if (kv0 + st * 16 + r16 >= kvlen) {
#pragma unroll
          for (int qs = 0; qs < 2; ++qs)
#pragma unroll
            for (int rg = 0; rg < 4; ++rg) sa[qs][st][rg] = -3e38f;
        }
    }

    float bad = 0.f;
    float m4v[2][4];
#pragma unroll
    for (int qs = 0; qs < 2; ++qs)
#pragma unroll
      for (int rg = 0; rg < 4; ++rg) {
        float m4 = fmaxf(fmaxf(sa[qs][0][rg], sa[qs][1][rg]),
                         fmaxf(sa[qs][2][rg], sa[qs][3][rg]));
        m4 = fmaxf(m4, fmaxf(fmaxf(sa[qs][4][rg], sa[qs][5][rg]),
                             fmaxf(sa[qs][6][rg], sa[qs][7][rg])));
        m4v[qs][rg] = m4;
        bad = fmaxf(bad, m4 - mi[qs][rg]);
      }
    if (__any(bad > 16.0f)) {
#pragma unroll
      for (int qs = 0; qs < 2; ++qs)
#pragma unroll
        for (int rg = 0; rg < 4; ++rg) {
          float mx = m4v[qs][rg];
#pragma unroll
          for (int off = 1; off < 16; off <<= 1) mx = fmaxf(mx, __shfl_xor(mx, off));
          const float nm = fmaxf(mi[qs][rg], mx);
          const float corr = __builtin_amdgcn_exp2f((mi[qs][rg] - nm) * C);
          mi[qs][rg] = nm;
          li[qs][rg] *= corr;
#pragma unroll
          for (int ds = 0; ds < 4; ++ds) oacc[qs][ds][rg] *= corr;
        }
    }

#pragma unroll
    for (int qs = 0; qs < 2; ++qs) {
#pragma unroll
      for (int rg = 0; rg < 4; ++rg) {
        const float mc = mi[qs][rg] * C;
        float p[8];
#pragma unroll
        for (int st = 0; st < 8; ++st)
          p[st] = __builtin_amdgcn_exp2f(__builtin_fmaf(sa[qs][st][rg], C, -mc));
        li[qs][rg] += ((p[0] + p[1]) + (p[2] + p[3])) + ((p[4] + p[5]) + (p[6] + p[7]));
        unsigned w0, w1, w2, w3;
        asm("v_cvt_pk_bf16_f32 %0, %1, %2" : "=v"(w0) : "v"(p[0]), "v"(p[1]));
        asm("v_cvt_pk_bf16_f32 %0, %1, %2" : "=v"(w1) : "v"(p[2]), "v"(p[3]));
        asm("v_cvt_pk_bf16_f32 %0, %1, %2" : "=v"(w2) : "v"(p[4]), "v"(p[5]));
        asm("v_cvt_pk_bf16_f32 %0, %1, %2" : "=v"(w3) : "v"(p[6]), "v"(p[7]));
        const int prow = qs * 16 + g * 4 + rg;
        uint2 pk0; pk0.x = w0; pk0.y = w1;
        uint2 pk1; pk1.x = w2; pk1.y = w3;
        *(uint2*)&Ps[wave][prow * 136 + r16 * 4]      = pk0;
        *(uint2*)&Ps[wave][prow * 136 + 64 + r16 * 4] = pk1;
      }
    }

    __builtin_amdgcn_s_setprio(1);
#pragma unroll
    for (int kc = 0; kc < 4; ++kc) {
      const bf16x8 pa0 = *(const bf16x8*)&Ps[wave][(r16)      * 136 + kc * 32 + g * 8];
      const bf16x8 pa1 = *(const bf16x8*)&Ps[wave][(16 + r16) * 136 + kc * 32 + g * 8];
#pragma unroll
      for (int ds = 0; ds < 4; ++ds) {
        const int dr = ds * 16 + r16;
        const int cc = kc * 4 + g;
        const int chs = cc ^ (dr & 15);
        const bf16x8 vf = *(const bf16x8*)&Vs[cur][dr * 128 + chs * 8];
        oacc[0][ds] = mfma16(pa0, vf, oacc[0][ds]);
        oacc[1][ds] = mfma16(pa1, vf, oacc[1][ds]);
      }
    }
    __builtin_amdgcn_s_setprio(0);

    __builtin_amdgcn_s_barrier();
  }

#pragma unroll
  for (int qs = 0; qs < 2; ++qs)
#pragma unroll
    for (int rg = 0; rg < 4; ++rg) {
      float s = li[qs][rg];
#pragma unroll
      for (int off = 1; off < 16; off <<= 1) s += __shfl_xor(s, off);
      li[qs][rg] = s;
    }

#pragma unroll
  for (int qs = 0; qs < 2; ++qs)
#pragma unroll
    for (int rg = 0; rg < 4; ++rg) {
      const float inv = 1.0f / li[qs][rg];
      const int row = q0 + qs * 16 + g * 4 + rg;
      const size_t base = (size_t)(b * SEQ + row) * DIMN + h * DHEAD;
#pragma unroll
      for (int ds = 0; ds < 4; ++ds)
        o[base + ds * 16 + r16] = f2bf(oacc[qs][ds][rg] * inv);
    }
}

extern "C" void kernel_launch(void* const* d_in, const int* in_sizes, int n_in,
                              void* d_out, int out_size, void* d_ws, size_t ws_size,
                              hipStream_t stream)
{
  const float* x   = (const float*)d_in[0];
  const float* ctx = (const float*)d_in[1];
  const float* Wq1 = (const float*)d_in[2];
  const float* Wk1 = (const float*)d_in[3];
  const float* Wv1 = (const float*)d_in[4];
  const float* Wo1 = (const float*)d_in[5];
  const float* bo1 = (const float*)d_in[6];
  const float* Wq2 = (const float*)d_in[7];
  const float* Wk2 = (const float*)d_in[8];
  const float* Wv2 = (const float*)d_in[9];
  const float* Wo2 = (const float*)d_in[10];
  const float* bo2 = (const float*)d_in[11];
  const float* Wp  = (const float*)d_in[12];
  const float* bp  = (const float*)d_in[13];
  const float* W2  = (const float*)d_in[14];
  const float* b2  = (const float*)d_in[15];
  const float* g1  = (const float*)d_in[16];
  const float* be1 = (const float*)d_in[17];
  const float* g2  = (const float*)d_in[18];
  const float* be2 = (const float*)d_in[19];
  const float* g3  = (const float*)d_in[20];
  const float* be3 = (const float*)d_in[21];

  char* ws = (char*)d_ws;
  size_t off = 0;
  auto alloc = [&](size_t bytes) -> void* {
    void* p = ws + off;
    off += (bytes + 255) & ~(size_t)255;
    return p;
  };

  u16* WqT1 = (u16*)alloc((size_t)1024 * 1024 * 2);
  u16* WkT1 = (u16*)alloc((size_t)1024 * 1024 * 2);
  u16* WvT1 = (u16*)alloc((size_t)1024 * 1024 * 2);
  u16* WoT1 = (u16*)alloc((size_t)1024 * 1024 * 2);
  u16* WqT2 = (u16*)alloc((size_t)1024 * 1024 * 2);
  u16* WkT2 = (u16*)alloc((size_t)1024 * 768 * 2);
  u16* WvT2 = (u16*)alloc((size_t)1024 * 768 * 2);
  u16* WoT2 = (u16*)alloc((size_t)1024 * 1024 * 2);
  u16* WpT  = (u16*)alloc((size_t)8192 * 1024 * 2);
  u16* W2T  = (u16*)alloc((size_t)1024 * 4096 * 2);
  u16* x1b  = (u16*)alloc((size_t)NTOK * DIMN * 2);
  u16* x2b  = (u16*)alloc((size_t)NTOK * DIMN * 2);
  u16* ctxb = (u16*)alloc((size_t)CTOK * CTXD * 2);
  u16* k2b  = (u16*)alloc((size_t)CTOK * DIMN * 2);
  u16* vt2b = (u16*)alloc((size_t)2 * HEADS * DHEAD * 128 * 2);
  u16* hb   = (u16*)alloc((size_t)NTOK * DIMN * 2);
  u16* qb   = (u16*)alloc((size_t)NTOK * DIMN * 2);
  u16* kb   = (u16*)alloc((size_t)NTOK * DIMN * 2);
  u16* vtb  = (u16*)alloc((size_t)NTOK * DIMN * 2);
  u16* ab   = (u16*)alloc((size_t)NTOK * DIMN * 2);
  u16* ub   = qb;

  dim3 blk(256);
  dim3 blk5(512);

  WAll wa;
  wa.nw = 10;
  const float* srcs[10] = {Wq1, Wk1, Wv1, Wo1, Wq2, Wo2, Wk2, Wv2, Wp, W2};
  u16* dsts[10]         = {WqT1, WkT1, WvT1, WoT1, WqT2, WoT2, WkT2, WvT2, WpT, W2T};
  const int Ksz[10]     = {1024, 1024, 1024, 1024, 1024, 1024, 768, 768, 1024, 4096};
  const int Nsz[10]     = {1024, 1024, 1024, 1024, 1024, 1024, 1024, 1024, 8192, 1024};
  int tot = 0;
  for (int i = 0; i < 10; ++i) {
    wa.start[i] = tot; wa.s[i] = srcs[i]; wa.d[i] = dsts[i];
    wa.K[i] = Ksz[i];  wa.N[i] = Nsz[i];
    tot += (Nsz[i] >> 6) * (Ksz[i] >> 6);
  }
  wa.lnStart = tot;
  wa.ccStart = tot + NTOK;
  wa.x = x; wa.g1 = g1; wa.be1 = be1; wa.hb = hb;
  wa.ctx = ctx; wa.ctxb = ctxb;
  const int ccBlocks = (CTOK * CTXD + 255) / 256;
  wconvA_k<<<dim3(tot + NTOK + ccBlocks), blk, 0, stream>>>(wa);

  // ---- self attention block
  qkv64_k<<<dim3(32, 24), blk5, 0, stream>>>(hb, WqT1, qb, kb, vtb);
  attn_k<<<dim3(8, 32), blk5, 0, stream>>>(qb, kb, vtb, ab, SEQ, SEQ, SEQ);
  gemm128_k<6><<<dim3(32, 8), blk5, 0, stream>>>(ab, WoT1, NTOK, 1024, 1024, bo1, x, nullptr, x1b, nullptr);

  // ---- cross attention block
  ln_b_k<<<NTOK, 256, 0, stream>>>(x1b, g2, be2, hb);
  q2kv2_k<<<dim3(288), blk5, 0, stream>>>(hb, WqT2, qb, ctxb, WkT2, k2b, vt2b);
  attn_k<<<dim3(8, 32), blk5, 0, stream>>>(qb, k2b, vt2b, ab, NCTX, NCTX, 128);
  gemm128_k<7><<<dim3(32, 8), blk5, 0, stream>>>(ab, WoT2, NTOK, 1024, 1024, bo2, nullptr, x1b, x2b, nullptr);

  // ---- GEGLU FF block
  ln_b_k<<<NTOK, 256, 0, stream>>>(x2b, g3, be3, hb);
  geglu_k<<<dim3(32, 32), blk5, 0, stream>>>(hb, WpT, WpT + (size_t)4096 * 1024, bp, bp + 4096, ub, NTOK, FFH);
  gemm128_k<8><<<dim3(32, 8), blk5, 0, stream>>>(ub, W2T, NTOK, 1024, 4096, b2, nullptr, x2b, nullptr, (float*)d_out);

  (void)in_sizes; (void)n_in; (void)out_size; (void)ws_size;
}

// Round 20
// 332.504 us; speedup vs baseline: 1.0246x; 1.0246x over previous
//
#include <hip/hip_runtime.h>
#include <hip/hip_bf16.h>
#include <math.h>

#define DIMN   1024
#define HEADS  16
#define DHEAD  64
#define CTXD   768
#define FFH    4096
#define NTOK   4096
#define SEQ    2048
#define NCTX   77
#define CTOK   154

typedef unsigned short u16;
typedef __bf16 bf16x8 __attribute__((ext_vector_type(8)));
typedef float  f32x4  __attribute__((ext_vector_type(4)));

__device__ __forceinline__ u16 f2bf(float f) {
  union { float f; unsigned u; } c; c.f = f;
  unsigned r = c.u + 0x7FFFu + ((c.u >> 16) & 1u);
  return (u16)(r >> 16);
}
__device__ __forceinline__ float bf2f(u16 h) {
  union { unsigned u; float f; } c; c.u = ((unsigned)h) << 16; return c.f;
}

__device__ __forceinline__ void gload16(const void* g, void* l) {
  __builtin_amdgcn_global_load_lds(
      (__attribute__((address_space(1))) void*)(void*)(g),
      (__attribute__((address_space(3))) void*)(l), 16, 0, 0);
}

__device__ __forceinline__ f32x4 mfma16(bf16x8 a, bf16x8 b, f32x4 c) {
  return __builtin_amdgcn_mfma_f32_16x16x32_bf16(a, b, c, 0, 0, 0);
}

// ---------------- prologue work-list: 10 weight transposes + LN1 + ctx conversion
struct WAll {
  int nw;
  int start[10];
  const float* s[10];
  u16* d[10];
  int K[10];
  int N[10];
  int lnStart, ccStart;
  const float* x; const float* g1; const float* be1; u16* hb;
  const float* ctx; u16* ctxb;
};

__global__ __launch_bounds__(256)
void wconvA_k(WAll wa)
{
  __shared__ u16 t[64][65];
  __shared__ float ss[4], qq[4];
  const int bid = blockIdx.x;
  const int tid = threadIdx.x;

  if (bid >= wa.ccStart) {
    const int i = (bid - wa.ccStart) * 256 + tid;
    if (i < CTOK * CTXD) wa.ctxb[i] = f2bf(wa.ctx[i]);
    return;
  }
  if (bid >= wa.lnStart) {
    const int row = bid - wa.lnStart;
    const float4 v = *(const float4*)&wa.x[(size_t)row * DIMN + tid * 4];
    float s = v.x + v.y + v.z + v.w;
    float q = v.x*v.x + v.y*v.y + v.z*v.z + v.w*v.w;
#pragma unroll
    for (int off = 32; off; off >>= 1) { s += __shfl_xor(s, off); q += __shfl_xor(q, off); }
    const int wave = tid >> 6;
    if ((tid & 63) == 0) { ss[wave] = s; qq[wave] = q; }
    __syncthreads();
    s = ss[0] + ss[1] + ss[2] + ss[3];
    q = qq[0] + qq[1] + qq[2] + qq[3];
    const float mu = s * (1.0f / DIMN);
    const float var = q * (1.0f / DIMN) - mu * mu;
    const float rs = rsqrtf(var + 1e-5f);
    const float4 gv = *(const float4*)&wa.g1[tid * 4];
    const float4 bv = *(const float4*)&wa.be1[tid * 4];
    ushort4 r;
    r.x = f2bf((v.x - mu) * rs * gv.x + bv.x);
    r.y = f2bf((v.y - mu) * rs * gv.y + bv.y);
    r.z = f2bf((v.z - mu) * rs * gv.z + bv.z);
    r.w = f2bf((v.w - mu) * rs * gv.w + bv.w);
    *(ushort4*)&wa.hb[(size_t)row * DIMN + tid * 4] = r;
    return;
  }

  int w = 0;
  while (w + 1 < wa.nw && bid >= wa.start[w + 1]) ++w;
  const int local = bid - wa.start[w];
  const float* __restrict__ W  = wa.s[w];
  u16* __restrict__       WT   = wa.d[w];
  const int K = wa.K[w], N = wa.N[w];
  const int tilesX = N >> 6;
  const int n0 = (local % tilesX) * 64;
  const int k0 = (local / tilesX) * 64;
  const int rr = tid >> 4, cc = tid & 15;
#pragma unroll
  for (int i = 0; i < 4; ++i) {
    int kr = rr + i * 16;
    const float4 v = *(const float4*)&W[(size_t)(k0 + kr) * N + n0 + cc * 4];
    t[kr][cc*4+0] = f2bf(v.x); t[kr][cc*4+1] = f2bf(v.y);
    t[kr][cc*4+2] = f2bf(v.z); t[kr][cc*4+3] = f2bf(v.w);
  }
  __syncthreads();
#pragma unroll
  for (int i = 0; i < 4; ++i) {
    int nr = rr + i * 16;
    int r0 = cc * 4;
    ushort4 o;
    o.x = t[r0+0][nr]; o.y = t[r0+1][nr]; o.z = t[r0+2][nr]; o.w = t[r0+3][nr];
    *(ushort4*)&WT[(size_t)(n0 + nr) * K + k0 + r0] = o;
  }
}

// ---------------- LayerNorm: bf16 row[1024] -> bf16
__global__ __launch_bounds__(256)
void ln_b_k(const u16* __restrict__ x, const float* __restrict__ gm,
            const float* __restrict__ bt, u16* __restrict__ o)
{
  int row = blockIdx.x;
  int tid = threadIdx.x;
  const ushort4 u = *(const ushort4*)&x[(size_t)row * DIMN + tid * 4];
  float4 v;
  v.x = bf2f(u.x); v.y = bf2f(u.y); v.z = bf2f(u.z); v.w = bf2f(u.w);
  float s = v.x + v.y + v.z + v.w;
  float q = v.x*v.x + v.y*v.y + v.z*v.z + v.w*v.w;
#pragma unroll
  for (int off = 32; off; off >>= 1) { s += __shfl_xor(s, off); q += __shfl_xor(q, off); }
  __shared__ float ss[4], qq[4];
  int wave = tid >> 6;
  if ((tid & 63) == 0) { ss[wave] = s; qq[wave] = q; }
  __syncthreads();
  s = ss[0] + ss[1] + ss[2] + ss[3];
  q = qq[0] + qq[1] + qq[2] + qq[3];
  float mu = s * (1.0f / DIMN);
  float var = q * (1.0f / DIMN) - mu * mu;
  float rs = rsqrtf(var + 1e-5f);
  const float4 gv = *(const float4*)&gm[tid * 4];
  const float4 bv = *(const float4*)&bt[tid * 4];
  ushort4 r;
  r.x = f2bf((v.x - mu) * rs * gv.x + bv.x);
  r.y = f2bf((v.y - mu) * rs * gv.y + bv.y);
  r.z = f2bf((v.z - mu) * rs * gv.z + bv.z);
  r.w = f2bf((v.w - mu) * rs * gv.w + bv.w);
  *(ushort4*)&o[(size_t)row * DIMN + tid * 4] = r;
}

// ---------------- QKV GEMM, BK=64: M=4096 N=3072 K=1024, routed epilogue
__global__ __launch_bounds__(512, 2)
void qkv64_k(const u16* __restrict__ A, const u16* __restrict__ Bt,
             u16* __restrict__ qb, u16* __restrict__ kb, u16* __restrict__ vtb)
{
  __shared__ __align__(16) u16 As[2][128 * 64];
  __shared__ __align__(16) u16 Bs[2][128 * 64];
  const int tid = threadIdx.x;
  const int lane = tid & 63, wave = tid >> 6;
  const int wr = wave >> 1, wc = wave & 1;
  const int g = lane >> 4, r16 = lane & 15;
  const int m0 = blockIdx.x * 128, n0 = blockIdx.y * 128;
  const int K = 1024;

  f32x4 acc[2][4] = {};

  int aro[2], bro[2], scs[2];
#pragma unroll
  for (int i = 0; i < 2; ++i) {
    const int c = tid + i * 512;
    const int r = c >> 3, ch = c & 7;
    scs[i] = ch ^ (r & 7);
    aro[i] = m0 + r;
    bro[i] = n0 + r;
  }

  auto stage = [&](int buf, int kt) {
#pragma unroll
    for (int i = 0; i < 2; ++i) {
      const int c = tid + i * 512;
      gload16(A  + (size_t)aro[i] * K + kt + scs[i] * 8, &As[buf][c * 8]);
      gload16(Bt + (size_t)bro[i] * K + kt + scs[i] * 8, &Bs[buf][c * 8]);
    }
  };

  stage(0, 0);

  const int nkt = K >> 6;
  for (int t = 0; t < nkt; ++t) {
    const int cur = t & 1;
    if (t + 1 < nkt) {
      stage(cur ^ 1, (t + 1) << 6);
      asm volatile("s_waitcnt vmcnt(4)" ::: "memory");
    } else {
      asm volatile("s_waitcnt vmcnt(0)" ::: "memory");
    }
    __builtin_amdgcn_s_barrier();

#pragma unroll
    for (int ks = 0; ks < 2; ++ks) {
      bf16x8 af[2], bfr[4];
#pragma unroll
      for (int mi = 0; mi < 2; ++mi) {
        int r = wr * 32 + mi * 16 + r16;
        int cph = (ks * 4 + g) ^ (r & 7);
        af[mi] = *(const bf16x8*)&As[cur][(r * 8 + cph) * 8];
      }
#pragma unroll
      for (int ni = 0; ni < 4; ++ni) {
        int r = wc * 64 + ni * 16 + r16;
        int cph = (ks * 4 + g) ^ (r & 7);
        bfr[ni] = *(const bf16x8*)&Bs[cur][(r * 8 + cph) * 8];
      }
      __builtin_amdgcn_s_setprio(1);
#pragma unroll
      for (int mi = 0; mi < 2; ++mi)
#pragma unroll
        for (int ni = 0; ni < 4; ++ni)
          acc[mi][ni] = mfma16(af[mi], bfr[ni], acc[mi][ni]);
      __builtin_amdgcn_s_setprio(0);
    }

    __builtin_amdgcn_s_barrier();
  }

  const int grp = n0 >> 10;
#pragma unroll
  for (int ni = 0; ni < 4; ++ni) {
    int col = n0 + wc * 64 + ni * 16 + r16;
    const int c1 = col & 1023;
#pragma unroll
    for (int mi = 0; mi < 2; ++mi) {
#pragma unroll
      for (int rg = 0; rg < 4; ++rg) {
        int row = m0 + wr * 32 + mi * 16 + g * 4 + rg;
        float v = acc[mi][ni][rg];
        if (grp == 0) {
          qb[(size_t)row * 1024 + c1] = f2bf(v);
        } else if (grp == 1) {
          kb[(size_t)row * 1024 + c1] = f2bf(v);
        } else {
          int b = row >> 11, srow_ = row & 2047;
          int jg = srow_ >> 6, j = srow_ & 63;
          int pos = jg * 64 + ((j & 15) << 2) + (j >> 4);
          vtb[((size_t)b * HEADS * DHEAD + c1) * SEQ + pos] = f2bf(v);
        }
      }
    }
  }
}

// ---------------- GEMM BK=128 for grid=256 (1 block/CU) epilogue GEMMs.
// MODE 6: out bf16 = acc + bias + residf (f32 resid)
// MODE 7: out bf16 = acc + bias + residb (bf16 resid)
// MODE 8: out f32  = acc + bias + residb (bf16 resid)
template<int MODE>
__global__ __launch_bounds__(512, 1)
void gemm128_k(const u16* __restrict__ A, const u16* __restrict__ Bt,
               int M, int N, int K,
               const float* __restrict__ bias, const float* __restrict__ residf,
               const u16* __restrict__ residb,
               u16* __restrict__ obf, float* __restrict__ of32)
{
  __shared__ __align__(16) u16 As[2][128 * 128];   // 64 KB
  __shared__ __align__(16) u16 Bs[2][128 * 128];   // 64 KB
  const int tid = threadIdx.x;
  const int lane = tid & 63, wave = tid >> 6;
  const int wr = wave >> 1, wc = wave & 1;
  const int g = lane >> 4, r16 = lane & 15;
  const int m0 = blockIdx.x * 128, n0 = blockIdx.y * 128;

  f32x4 acc[2][4] = {};

  int aro[4], bro[4], scs[4];
#pragma unroll
  for (int i = 0; i < 4; ++i) {
    const int c = tid + i * 512;
    const int r = c >> 4, ch = c & 15;
    scs[i] = ch ^ (r & 15);
    aro[i] = m0 + r;
    bro[i] = n0 + r;
  }

  auto stage = [&](int buf, int kt) {
#pragma unroll
    for (int i = 0; i < 4; ++i) {
      const int c = tid + i * 512;
      gload16(A  + (size_t)aro[i] * K + kt + scs[i] * 8, &As[buf][c * 8]);
      gload16(Bt + (size_t)bro[i] * K + kt + scs[i] * 8, &Bs[buf][c * 8]);
    }
  };

  stage(0, 0);

  const int nkt = K >> 7;
  for (int t = 0; t < nkt; ++t) {
    const int cur = t & 1;
    if (t + 1 < nkt) {
      stage(cur ^ 1, (t + 1) << 7);
      asm volatile("s_waitcnt vmcnt(8)" ::: "memory");
    } else {
      asm volatile("s_waitcnt vmcnt(0)" ::: "memory");
    }
    __builtin_amdgcn_s_barrier();

#pragma unroll
    for (int ks = 0; ks < 4; ++ks) {
      bf16x8 af[2], bfr[4];
#pragma unroll
      for (int mi = 0; mi < 2; ++mi) {
        int r = wr * 32 + mi * 16 + r16;
        int cph = (ks * 4 + g) ^ (r & 15);
        af[mi] = *(const bf16x8*)&As[cur][(r * 16 + cph) * 8];
      }
#pragma unroll
      for (int ni = 0; ni < 4; ++ni) {
        int r = wc * 64 + ni * 16 + r16;
        int cph = (ks * 4 + g) ^ (r & 15);
        bfr[ni] = *(const bf16x8*)&Bs[cur][(r * 16 + cph) * 8];
      }
      __builtin_amdgcn_s_setprio(1);
#pragma unroll
      for (int mi = 0; mi < 2; ++mi)
#pragma unroll
        for (int ni = 0; ni < 4; ++ni)
          acc[mi][ni] = mfma16(af[mi], bfr[ni], acc[mi][ni]);
      __builtin_amdgcn_s_setprio(0);
    }

    __builtin_amdgcn_s_barrier();
  }

#pragma unroll
  for (int ni = 0; ni < 4; ++ni) {
    int col = n0 + wc * 64 + ni * 16 + r16;
    float bv = bias[col];
#pragma unroll
    for (int mi = 0; mi < 2; ++mi) {
      f32x4 c = acc[mi][ni];
#pragma unroll
      for (int rg = 0; rg < 4; ++rg) {
        int row = m0 + wr * 32 + mi * 16 + g * 4 + rg;
        size_t o = (size_t)row * N + col;
        float v = c[rg] + bv;
        if constexpr (MODE == 6) {
          obf[o] = f2bf(v + residf[o]);
        } else if constexpr (MODE == 7) {
          obf[o] = f2bf(v + bf2f(residb[o]));
        } else {  // MODE 8
          of32[o] = v + bf2f(residb[o]);
        }
      }
    }
  }
}

// ---------------- merged Q2 (BK=64, 256 blocks) + KV2 (BK=32, 32 blocks)
// grid = 288 x 512 threads  (R18-proven: 2 blocks/CU, all co-resident)
__global__ __launch_bounds__(512, 2)
void q2kv2_k(const u16* __restrict__ hb, const u16* __restrict__ WqT2,
             u16* __restrict__ qb,
             const u16* __restrict__ ctxb, const u16* __restrict__ WkT2,
             u16* __restrict__ k2b, u16* __restrict__ vt2b)
{
  __shared__ __align__(16) u16 AsB[2][128 * 64];
  __shared__ __align__(16) u16 BsB[2][128 * 64];
  const int tid = threadIdx.x;
  const int lane = tid & 63, wave = tid >> 6;
  const int wr = wave >> 1, wc = wave & 1;
  const int g = lane >> 4, r16 = lane & 15;
  const int bid = blockIdx.x;

  if (bid < 256) {
    const int K = 1024;
    const int m0 = (bid & 31) * 128, n0 = (bid >> 5) * 128;
    f32x4 acc[2][4] = {};

    int aro[2], bro[2], scs[2];
#pragma unroll
    for (int i = 0; i < 2; ++i) {
      const int c = tid + i * 512;
      const int r = c >> 3, ch = c & 7;
      scs[i] = ch ^ (r & 7);
      aro[i] = m0 + r;
      bro[i] = n0 + r;
    }
    auto stage = [&](int buf, int kt) {
#pragma unroll
      for (int i = 0; i < 2; ++i) {
        const int c = tid + i * 512;
        gload16(hb   + (size_t)aro[i] * K + kt + scs[i] * 8, &AsB[buf][c * 8]);
        gload16(WqT2 + (size_t)bro[i] * K + kt + scs[i] * 8, &BsB[buf][c * 8]);
      }
    };
    stage(0, 0);
    const int nkt = K >> 6;
    for (int t = 0; t < nkt; ++t) {
      const int cur = t & 1;
      if (t + 1 < nkt) {
        stage(cur ^ 1, (t + 1) << 6);
        asm volatile("s_waitcnt vmcnt(4)" ::: "memory");
      } else {
        asm volatile("s_waitcnt vmcnt(0)" ::: "memory");
      }
      __builtin_amdgcn_s_barrier();
#pragma unroll
      for (int ks = 0; ks < 2; ++ks) {
        bf16x8 af[2], bfr[4];
#pragma unroll
        for (int mi = 0; mi < 2; ++mi) {
          int r = wr * 32 + mi * 16 + r16;
          int cph = (ks * 4 + g) ^ (r & 7);
          af[mi] = *(const bf16x8*)&AsB[cur][(r * 8 + cph) * 8];
        }
#pragma unroll
        for (int ni = 0; ni < 4; ++ni) {
          int r = wc * 64 + ni * 16 + r16;
          int cph = (ks * 4 + g) ^ (r & 7);
          bfr[ni] = *(const bf16x8*)&BsB[cur][(r * 8 + cph) * 8];
        }
        __builtin_amdgcn_s_setprio(1);
#pragma unroll
        for (int mi = 0; mi < 2; ++mi)
#pragma unroll
          for (int ni = 0; ni < 4; ++ni)
            acc[mi][ni] = mfma16(af[mi], bfr[ni], acc[mi][ni]);
        __builtin_amdgcn_s_setprio(0);
      }
      __builtin_amdgcn_s_barrier();
    }
#pragma unroll
    for (int ni = 0; ni < 4; ++ni) {
      int col = n0 + wc * 64 + ni * 16 + r16;
#pragma unroll
      for (int mi = 0; mi < 2; ++mi) {
#pragma unroll
        for (int rg = 0; rg < 4; ++rg) {
          int row = m0 + wr * 32 + mi * 16 + g * 4 + rg;
          qb[(size_t)row * 1024 + col] = f2bf(acc[mi][ni][rg]);
        }
      }
    }
  } else {
    const int K = 768, M = CTOK;
    const int local = bid - 256;
    const int m0 = (local & 1) * 128, n0 = (local >> 1) * 128;
    u16* As = &AsB[0][0];
    u16* Bs = &BsB[0][0];
    const int BUFS = 128 * 32;
    f32x4 acc[2][4] = {};

    const int srow = tid >> 2;
    const int sch  = tid & 3;
    const int schs = sch ^ ((srow >> 1) & 3);
    const int arow = (m0 + srow > M - 1) ? (M - 1) : (m0 + srow);
    const size_t abase = (size_t)arow * K + schs * 8;
    const size_t bbase = (size_t)(n0 + srow) * K + schs * 8;

    auto stage = [&](int buf, int kt) {
      gload16(ctxb + abase + kt, &As[buf * BUFS + tid * 8]);
      gload16(WkT2 + bbase + kt, &Bs[buf * BUFS + tid * 8]);
    };
    stage(0, 0);
    const int nkt = K >> 5;
    for (int t = 0; t < nkt; ++t) {
      const int cur = t & 1;
      if (t + 1 < nkt) {
        stage(cur ^ 1, (t + 1) << 5);
        asm volatile("s_waitcnt vmcnt(2)" ::: "memory");
      } else {
        asm volatile("s_waitcnt vmcnt(0)" ::: "memory");
      }
      __builtin_amdgcn_s_barrier();

      bf16x8 af[2], bfr[4];
#pragma unroll
      for (int mi = 0; mi < 2; ++mi) {
        int r = wr * 32 + mi * 16 + r16;
        int cph = g ^ ((r >> 1) & 3);
        af[mi] = *(const bf16x8*)&As[cur * BUFS + (r * 4 + cph) * 8];
      }
#pragma unroll
      for (int ni = 0; ni < 4; ++ni) {
        int r = wc * 64 + ni * 16 + r16;
        int cph = g ^ ((r >> 1) & 3);
        bfr[ni] = *(const bf16x8*)&Bs[cur * BUFS + (r * 4 + cph) * 8];
      }
      __builtin_amdgcn_s_setprio(1);
#pragma unroll
      for (int mi = 0; mi < 2; ++mi)
#pragma unroll
        for (int ni = 0; ni < 4; ++ni)
          acc[mi][ni] = mfma16(af[mi], bfr[ni], acc[mi][ni]);
      __builtin_amdgcn_s_setprio(0);

      __builtin_amdgcn_s_barrier();
    }

    const int grp = n0 >> 10;
#pragma unroll
    for (int ni = 0; ni < 4; ++ni) {
      int col = n0 + wc * 64 + ni * 16 + r16;
      const int c1 = col & 1023;
#pragma unroll
      for (int mi = 0; mi < 2; ++mi) {
#pragma unroll
        for (int rg = 0; rg < 4; ++rg) {
          int row = m0 + wr * 32 + mi * 16 + g * 4 + rg;
          if (row < M) {
            float v = acc[mi][ni][rg];
            if (grp == 0) {
              k2b[(size_t)row * 1024 + c1] = f2bf(v);
            } else {
              int b = row / NCTX, srow_ = row - b * NCTX;
              int jg = srow_ >> 6, j = srow_ & 63;
              int pos = jg * 64 + ((j & 15) << 2) + (j >> 4);
              vt2b[((size_t)b * HEADS * DHEAD + c1) * 128 + pos] = f2bf(v);
            }
          }
        }
      }
    }
  }
}

// ---------------- fused GEGLU GEMM: 512 thr, 128x128, 2-buf counted vmcnt, XCD swizzle
__global__ __launch_bounds__(512, 2)
void geglu_k(const u16* __restrict__ A, const u16* __restrict__ B1t,
             const u16* __restrict__ B2t,
             const float* __restrict__ ba, const float* __restrict__ bg,
             u16* __restrict__ out, int M, int N)
{
  __shared__ __align__(16) u16 As[2][128 * 32];
  __shared__ __align__(16) u16 B1s[2][128 * 32];
  __shared__ __align__(16) u16 B2s[2][128 * 32];
  const int tid = threadIdx.x;
  const int lane = tid & 63, wave = tid >> 6;
  const int wr = wave >> 1, wc = wave & 1;
  const int g = lane >> 4, r16 = lane & 15;
  {
    const int gx = gridDim.x;
    const int nwg = gx * gridDim.y;
    const int L = blockIdx.y * gx + blockIdx.x;
    const int nl = (L & 7) * (nwg >> 3) + (L >> 3);
    const int bx = nl % gx, by = nl / gx;
    const int m0 = bx * 128, n0 = by * 128;
    const int K = 1024;

    f32x4 acca[2][4] = {}, accg[2][4] = {};

    const int srow = tid >> 2;
    const int sch  = tid & 3;
    const int schs = sch ^ ((srow >> 1) & 3);
    const size_t abase = (size_t)(m0 + srow) * K + schs * 8;
    const size_t bbase = (size_t)(n0 + srow) * K + schs * 8;

    auto stage = [&](int buf, int kt) {
      gload16(A   + abase + kt, &As[buf][tid * 8]);
      gload16(B1t + bbase + kt, &B1s[buf][tid * 8]);
      gload16(B2t + bbase + kt, &B2s[buf][tid * 8]);
    };

    stage(0, 0);

    const int nkt = K >> 5;
    for (int t = 0; t < nkt; ++t) {
      const int cur = t & 1;
      if (t + 1 < nkt) {
        stage(cur ^ 1, (t + 1) << 5);
        asm volatile("s_waitcnt vmcnt(3)" ::: "memory");
      } else {
        asm volatile("s_waitcnt vmcnt(0)" ::: "memory");
      }
      __builtin_amdgcn_s_barrier();

      bf16x8 af[2], b1f[4], b2f[4];
#pragma unroll
      for (int mi = 0; mi < 2; ++mi) {
        int r = wr * 32 + mi * 16 + r16;
        int cph = g ^ ((r >> 1) & 3);
        af[mi] = *(const bf16x8*)&As[cur][(r * 4 + cph) * 8];
      }
#pragma unroll
      for (int ni = 0; ni < 4; ++ni) {
        int r = wc * 64 + ni * 16 + r16;
        int cph = g ^ ((r >> 1) & 3);
        b1f[ni] = *(const bf16x8*)&B1s[cur][(r * 4 + cph) * 8];
        b2f[ni] = *(const bf16x8*)&B2s[cur][(r * 4 + cph) * 8];
      }
      __builtin_amdgcn_s_setprio(1);
#pragma unroll
      for (int mi = 0; mi < 2; ++mi)
#pragma unroll
        for (int ni = 0; ni < 4; ++ni) {
          acca[mi][ni] = mfma16(af[mi], b1f[ni], acca[mi][ni]);
          accg[mi][ni] = mfma16(af[mi], b2f[ni], accg[mi][ni]);
        }
      __builtin_amdgcn_s_setprio(0);

      __builtin_amdgcn_s_barrier();
    }

#pragma unroll
    for (int ni = 0; ni < 4; ++ni) {
      int col = n0 + wc * 64 + ni * 16 + r16;
      float bva = ba[col], bvg = bg[col];
#pragma unroll
      for (int mi = 0; mi < 2; ++mi) {
#pragma unroll
        for (int rg = 0; rg < 4; ++rg) {
          int row = m0 + wr * 32 + mi * 16 + g * 4 + rg;
          float a  = acca[mi][ni][rg] + bva;
          float gt = accg[mi][ni][rg] + bvg;
          float gl = 0.5f * gt * (1.0f + erff(gt * 0.70710678f));
          out[(size_t)row * N + col] = f2bf(a * gl);
        }
      }
    }
  }
}

// ---------------- flash attention v6: 8 waves (256 q/block), KVBLK=128, XCD-affine
// grid MUST be (8, 32)
__global__ __launch_bounds__(512, 1)
void attn_k(const u16* __restrict__ q, const u16* __restrict__ k,
            const u16* __restrict__ vt, u16* __restrict__ o,
            int kvlen, int seqk, int vstride)
{
  __shared__ __align__(16) u16 Ks[2][128 * 64];
  __shared__ __align__(16) u16 Vs[2][64 * 128];
  __shared__ __align__(16) u16 Ps[8][32 * 136];
  const int tid = threadIdx.x, lane = tid & 63, wave = tid >> 6;
  const int g = lane >> 4, r16 = lane & 15;

  const int L  = blockIdx.y * 8 + blockIdx.x;
  const int c8 = L & 7, tt = L >> 3;
  const int bx = tt & 7;
  const int bh = c8 * 4 + (tt >> 3);

  const int b = bh >> 4, h = bh & 15;
  const int q0 = bx * 256 + wave * 32;
  const float C = 0.18033688f;

  bf16x8 aq[2][2];
#pragma unroll
  for (int qs = 0; qs < 2; ++qs) {
    const size_t qoff = (size_t)(b * SEQ + q0 + qs * 16 + r16) * DIMN + h * DHEAD;
#pragma unroll
    for (int kc = 0; kc < 2; ++kc)
      aq[qs][kc] = *(const bf16x8*)&q[qoff + kc * 32 + g * 8];
  }
  asm volatile("" :: "v"(aq[0][0]), "v"(aq[0][1]), "v"(aq[1][0]), "v"(aq[1][1]));

  f32x4 oacc[2][4] = {};
  float mi[2][4], li[2][4];
#pragma unroll
  for (int qs = 0; qs < 2; ++qs)
#pragma unroll
    for (int rg = 0; rg < 4; ++rg) { mi[qs][rg] = -3e38f; li[qs][rg] = 0.f; }

  const size_t vtbase = (size_t)(b * HEADS + h) * DHEAD * vstride;
  const size_t kbase  = (size_t)b * seqk * DIMN + h * DHEAD;
  const int nkv = (kvlen + 127) >> 7;

  auto stage = [&](int buf, int kv0) {
#pragma unroll
    for (int i = 0; i < 2; ++i) {
      const int c = tid + i * 512;
      const int row = c >> 3, ch = c & 7;
      const int chs = ch ^ (row & 7);
      int kr = kv0 + row; if (kr > kvlen - 1) kr = kvlen - 1;
      gload16(k + kbase + (size_t)kr * DIMN + chs * 8, &Ks[buf][c * 8]);
    }
#pragma unroll
    for (int i = 0; i < 2; ++i) {
      const int c = tid + i * 512;
      const int row = c >> 4, ch = c & 15;
      const int chs = ch ^ (row & 15);
      gload16(vt + vtbase + (size_t)row * vstride + kv0 + chs * 8, &Vs[buf][c * 8]);
    }
  };

  stage(0, 0);

  for (int kvb = 0; kvb < nkv; ++kvb) {
    const int kv0 = kvb * 128;
    const int cur = kvb & 1;
    if (kvb + 1 < nkv) {
      stage(cur ^ 1, kv0 + 128);
      asm volatile("s_waitcnt vmcnt(4)" ::: "memory");
    } else {
      asm volatile("s_waitcnt vmcnt(0)" ::: "memory");
    }
    __builtin_amdgcn_s_barrier();

    f32x4 sa[2][8];
#pragma unroll
    for (int qs = 0; qs < 2; ++qs)
#pragma unroll
      for (int st = 0; st < 8; ++st) sa[qs][st] = (f32x4){0.f, 0.f, 0.f, 0.f};
    __builtin_amdgcn_s_setprio(1);
#pragma unroll
    for (int st = 0; st < 8; ++st) {
      const int kvr = st * 16 + r16;
#pragma unroll
      for (int kc = 0; kc < 2; ++kc) {
        const int chs = (kc * 4 + g) ^ (kvr & 7);
        const bf16x8 kf = *(const bf16x8*)&Ks[cur][kvr * 64 + chs * 8];
        sa[0][st] = mfma16(aq[0][kc], kf, sa[0][st]);
        sa[1][st] = mfma16(aq[1][kc], kf, sa[1][st]);
      }
    }
    __builtin_amdgcn_s_setprio(0);

    if (kv0 + 128 > kvlen) {
#pragma unroll
      for (int st = 0; st < 8; ++st)
        if (kv0 + st * 16 + r16 >= kvlen) {
#pragma unroll
          for (int qs = 0; qs < 2; ++qs)
#pragma unroll
            for (int rg = 0; rg < 4; ++rg) sa[qs][st][rg] = -3e38f;
        }
    }

    float bad = 0.f;
    float m4v[2][4];
#pragma unroll
    for (int qs = 0; qs < 2; ++qs)
#pragma unroll
      for (int rg = 0; rg < 4; ++rg) {
        float m4 = fmaxf(fmaxf(sa[qs][0][rg], sa[qs][1][rg]),
                         fmaxf(sa[qs][2][rg], sa[qs][3][rg]));
        m4 = fmaxf(m4, fmaxf(fmaxf(sa[qs][4][rg], sa[qs][5][rg]),
                             fmaxf(sa[qs][6][rg], sa[qs][7][rg])));
        m4v[qs][rg] = m4;
        bad = fmaxf(bad, m4 - mi[qs][rg]);
      }
    if (__any(bad > 16.0f)) {
#pragma unroll
      for (int qs = 0; qs < 2; ++qs)
#pragma unroll
        for (int rg = 0; rg < 4; ++rg) {
          float mx = m4v[qs][rg];
#pragma unroll
          for (int off = 1; off < 16; off <<= 1) mx = fmaxf(mx, __shfl_xor(mx, off));
          const float nm = fmaxf(mi[qs][rg], mx);
          const float corr = __builtin_amdgcn_exp2f((mi[qs][rg] - nm) * C);
          mi[qs][rg] = nm;
          li[qs][rg] *= corr;
#pragma unroll
          for (int ds = 0; ds < 4; ++ds) oacc[qs][ds][rg] *= corr;
        }
    }

#pragma unroll
    for (int qs = 0; qs < 2; ++qs) {
#pragma unroll
      for (int rg = 0; rg < 4; ++rg) {
        const float mc = mi[qs][rg] * C;
        float p[8];
#pragma unroll
        for (int st = 0; st < 8; ++st)
          p[st] = __builtin_amdgcn_exp2f(__builtin_fmaf(sa[qs][st][rg], C, -mc));
        li[qs][rg] += ((p[0] + p[1]) + (p[2] + p[3])) + ((p[4] + p[5]) + (p[6] + p[7]));
        unsigned w0, w1, w2, w3;
        asm("v_cvt_pk_bf16_f32 %0, %1, %2" : "=v"(w0) : "v"(p[0]), "v"(p[1]));
        asm("v_cvt_pk_bf16_f32 %0, %1, %2" : "=v"(w1) : "v"(p[2]), "v"(p[3]));
        asm("v_cvt_pk_bf16_f32 %0, %1, %2" : "=v"(w2) : "v"(p[4]), "v"(p[5]));
        asm("v_cvt_pk_bf16_f32 %0, %1, %2" : "=v"(w3) : "v"(p[6]), "v"(p[7]));
        const int prow = qs * 16 + g * 4 + rg;
        uint2 pk0; pk0.x = w0; pk0.y = w1;
        uint2 pk1; pk1.x = w2; pk1.y = w3;
        *(uint2*)&Ps[wave][prow * 136 + r16 * 4]      = pk0;
        *(uint2*)&Ps[wave][prow * 136 + 64 + r16 * 4] = pk1;
      }
    }

    __builtin_amdgcn_s_setprio(1);
#pragma unroll
    for (int kc = 0; kc < 4; ++kc) {
      const bf16x8 pa0 = *(const bf16x8*)&Ps[wave][(r16)      * 136 + kc * 32 + g * 8];
      const bf16x8 pa1 = *(const bf16x8*)&Ps[wave][(16 + r16) * 136 + kc * 32 + g * 8];
#pragma unroll
      for (int ds = 0; ds < 4; ++ds) {
        const int dr = ds * 16 + r16;
        const int cc = kc * 4 + g;
        const int chs = cc ^ (dr & 15);
        const bf16x8 vf = *(const bf16x8*)&Vs[cur][dr * 128 + chs * 8];
        oacc[0][ds] = mfma16(pa0, vf, oacc[0][ds]);
        oacc[1][ds] = mfma16(pa1, vf, oacc[1][ds]);
      }
    }
    __builtin_amdgcn_s_setprio(0);

    __builtin_amdgcn_s_barrier();
  }

#pragma unroll
  for (int qs = 0; qs < 2; ++qs)
#pragma unroll
    for (int rg = 0; rg < 4; ++rg) {
      float s = li[qs][rg];
#pragma unroll
      for (int off = 1; off < 16; off <<= 1) s += __shfl_xor(s, off);
      li[qs][rg] = s;
    }

#pragma unroll
  for (int qs = 0; qs < 2; ++qs)
#pragma unroll
    for (int rg = 0; rg < 4; ++rg) {
      const float inv = 1.0f / li[qs][rg];
      const int row = q0 + qs * 16 + g * 4 + rg;
      const size_t base = (size_t)(b * SEQ + row) * DIMN + h * DHEAD;
#pragma unroll
      for (int ds = 0; ds < 4; ++ds)
        o[base + ds * 16 + r16] = f2bf(oacc[qs][ds][rg] * inv);
    }
}

extern "C" void kernel_launch(void* const* d_in, const int* in_sizes, int n_in,
                              void* d_out, int out_size, void* d_ws, size_t ws_size,
                              hipStream_t stream)
{
  const float* x   = (const float*)d_in[0];
  const float* ctx = (const float*)d_in[1];
  const float* Wq1 = (const float*)d_in[2];
  const float* Wk1 = (const float*)d_in[3];
  const float* Wv1 = (const float*)d_in[4];
  const float* Wo1 = (const float*)d_in[5];
  const float* bo1 = (const float*)d_in[6];
  const float* Wq2 = (const float*)d_in[7];
  const float* Wk2 = (const float*)d_in[8];
  const float* Wv2 = (const float*)d_in[9];
  const float* Wo2 = (const float*)d_in[10];
  const float* bo2 = (const float*)d_in[11];
  const float* Wp  = (const float*)d_in[12];
  const float* bp  = (const float*)d_in[13];
  const float* W2  = (const float*)d_in[14];
  const float* b2  = (const float*)d_in[15];
  const float* g1  = (const float*)d_in[16];
  const float* be1 = (const float*)d_in[17];
  const float* g2  = (const float*)d_in[18];
  const float* be2 = (const float*)d_in[19];
  const float* g3  = (const float*)d_in[20];
  const float* be3 = (const float*)d_in[21];

  char* ws = (char*)d_ws;
  size_t off = 0;
  auto alloc = [&](size_t bytes) -> void* {
    void* p = ws + off;
    off += (bytes + 255) & ~(size_t)255;
    return p;
  };

  u16* WqT1 = (u16*)alloc((size_t)1024 * 1024 * 2);
  u16* WkT1 = (u16*)alloc((size_t)1024 * 1024 * 2);
  u16* WvT1 = (u16*)alloc((size_t)1024 * 1024 * 2);
  u16* WoT1 = (u16*)alloc((size_t)1024 * 1024 * 2);
  u16* WqT2 = (u16*)alloc((size_t)1024 * 1024 * 2);
  u16* WkT2 = (u16*)alloc((size_t)1024 * 768 * 2);
  u16* WvT2 = (u16*)alloc((size_t)1024 * 768 * 2);
  u16* WoT2 = (u16*)alloc((size_t)1024 * 1024 * 2);
  u16* WpT  = (u16*)alloc((size_t)8192 * 1024 * 2);
  u16* W2T  = (u16*)alloc((size_t)1024 * 4096 * 2);
  u16* x1b  = (u16*)alloc((size_t)NTOK * DIMN * 2);
  u16* x2b  = (u16*)alloc((size_t)NTOK * DIMN * 2);
  u16* ctxb = (u16*)alloc((size_t)CTOK * CTXD * 2);
  u16* k2b  = (u16*)alloc((size_t)CTOK * DIMN * 2);
  u16* vt2b = (u16*)alloc((size_t)2 * HEADS * DHEAD * 128 * 2);
  u16* hb   = (u16*)alloc((size_t)NTOK * DIMN * 2);
  u16* qb   = (u16*)alloc((size_t)NTOK * DIMN * 2);
  u16* kb   = (u16*)alloc((size_t)NTOK * DIMN * 2);
  u16* vtb  = (u16*)alloc((size_t)NTOK * DIMN * 2);
  u16* ab   = (u16*)alloc((size_t)NTOK * DIMN * 2);
  u16* ub   = qb;

  dim3 blk(256);
  dim3 blk5(512);

  WAll wa;
  wa.nw = 10;
  const float* srcs[10] = {Wq1, Wk1, Wv1, Wo1, Wq2, Wo2, Wk2, Wv2, Wp, W2};
  u16* dsts[10]         = {WqT1, WkT1, WvT1, WoT1, WqT2, WoT2, WkT2, WvT2, WpT, W2T};
  const int Ksz[10]     = {1024, 1024, 1024, 1024, 1024, 1024, 768, 768, 1024, 4096};
  const int Nsz[10]     = {1024, 1024, 1024, 1024, 1024, 1024, 1024, 1024, 8192, 1024};
  int tot = 0;
  for (int i = 0; i < 10; ++i) {
    wa.start[i] = tot; wa.s[i] = srcs[i]; wa.d[i] = dsts[i];
    wa.K[i] = Ksz[i];  wa.N[i] = Nsz[i];
    tot += (Nsz[i] >> 6) * (Ksz[i] >> 6);
  }
  wa.lnStart = tot;
  wa.ccStart = tot + NTOK;
  wa.x = x; wa.g1 = g1; wa.be1 = be1; wa.hb = hb;
  wa.ctx = ctx; wa.ctxb = ctxb;
  const int ccBlocks = (CTOK * CTXD + 255) / 256;
  wconvA_k<<<dim3(tot + NTOK + ccBlocks), blk, 0, stream>>>(wa);

  // ---- self attention block
  qkv64_k<<<dim3(32, 24), blk5, 0, stream>>>(hb, WqT1, qb, kb, vtb);
  attn_k<<<dim3(8, 32), blk5, 0, stream>>>(qb, kb, vtb, ab, SEQ, SEQ, SEQ);
  gemm128_k<6><<<dim3(32, 8), blk5, 0, stream>>>(ab, WoT1, NTOK, 1024, 1024, bo1, x, nullptr, x1b, nullptr);

  // ---- cross attention block
  ln_b_k<<<NTOK, 256, 0, stream>>>(x1b, g2, be2, hb);
  q2kv2_k<<<dim3(288), blk5, 0, stream>>>(hb, WqT2, qb, ctxb, WkT2, k2b, vt2b);
  attn_k<<<dim3(8, 32), blk5, 0, stream>>>(qb, k2b, vt2b, ab, NCTX, NCTX, 128);
  gemm128_k<7><<<dim3(32, 8), blk5, 0, stream>>>(ab, WoT2, NTOK, 1024, 1024, bo2, nullptr, x1b, x2b, nullptr);

  // ---- GEGLU FF block
  ln_b_k<<<NTOK, 256, 0, stream>>>(x2b, g3, be3, hb);
  geglu_k<<<dim3(32, 32), blk5, 0, stream>>>(hb, WpT, WpT + (size_t)4096 * 1024, bp, bp + 4096, ub, NTOK, FFH);
  gemm128_k<8><<<dim3(32, 8), blk5, 0, stream>>>(ub, W2T, NTOK, 1024, 4096, b2, nullptr, x2b, nullptr, (float*)d_out);

  (void)in_sizes; (void)n_in; (void)out_size; (void)ws_size;
}